// Round 32
// baseline (65.807 us; speedup 1.0000x reference)
//
#include <hip/hip_runtime.h>

#define NN 50000
#define NE 300000
#define KDIM 256
#define FDIM 64
#define CAP 48              // max degree capacity; P(deg>47)~1e-30 for multinomial(6)
#define NTILES16 (NN / 16)  // 3125 row-tiles for MFMA gemm
#define SCAT_BLKS ((NE + 255) / 256)          // 1172
#define GEMM_BLKS ((NTILES16 + 1) / 2)        // 1563
#define FUSE_BLKS (SCAT_BLKS + GEMM_BLKS)     // 2735 = 7*390 + 5

typedef __attribute__((ext_vector_type(8))) short bf16x8;
typedef __attribute__((ext_vector_type(4))) float f32x4;

static __device__ __forceinline__ unsigned short bf16_of(float f) {
  union { float f; unsigned u; } v; v.f = f;
  unsigned r = (v.u + 0x7fffu + ((v.u >> 16) & 1u)) >> 16;  // RTNE
  return (unsigned short)r;
}
static __device__ __forceinline__ void unpack2(unsigned u, float& lo, float& hi) {
  union { unsigned u; float f; } a, b;
  a.u = u << 16; b.u = u & 0xffff0000u;
  lo = a.f; hi = b.f;
}
static __device__ __forceinline__ unsigned pack2(float lo, float hi) {
  return (unsigned)bf16_of(lo) | ((unsigned)bf16_of(hi) << 16);
}

// async global->LDS, 16B per lane: LDS dest = wave-uniform base + lane*16.
static __device__ __forceinline__ void gload_lds16(const float* g, void* l) {
  __builtin_amdgcn_global_load_lds(
      (const __attribute__((address_space(1))) void*)g,
      (__attribute__((address_space(3))) void*)l, 16, 0, 0);
}

// ---------- init: zero cnt (blocks 0..195) + W->bf16 (blocks 196..259) ----------
__global__ __launch_bounds__(256) void init_kernel(int* __restrict__ cnt,
    const float* __restrict__ W, unsigned short* __restrict__ wbf) {
  int b = blockIdx.x, t = threadIdx.x;
  if (b < 196) {
    int i = b * 256 + t;
    if (i < NN) cnt[i] = 0;
  } else {
    int i = (b - 196) * 256 + t;    // 64 blocks * 256 = 16384 = FDIM*KDIM
    wbf[i] = bf16_of(W[i]);
  }
}

// ---------- fused: scatter || gemm, INTERLEAVED roles, 32KB LDS ----------
// R30: interleave {3 scat, 4 gemm}/7 -> co-residency (-5.5us). R32: union the
// K-split reduction buffer onto the (dead-by-then) staging buffer: LDS 40->32KB
// -> 5 blocks/CU (was 4), +25% resident blocks for the overlap.
// Extra __syncthreads separates last xs read from first red write (WAR).
// gemm emits RAW Y = x@W^T (bf16); dinv deferred to hops:
//   out = D^-1/2 (A+I) D^-1 (A+I) D^-1/2 Y.
// C/D: col=lane&15, row=(lane>>4)*4+reg (HW-verified m89).
__global__ __launch_bounds__(256) void fused_kernel(
    const int* __restrict__ src, const int* __restrict__ dst,
    int* __restrict__ cnt, int* __restrict__ col,
    const float* __restrict__ x, const unsigned short* __restrict__ wbf,
    unsigned short* __restrict__ yh) {
  __shared__ float4 xs[4][8][64];            // 32 KB; red aliases this after use
  float* red = (float*)&xs[0][0][0];         // red[(tib*16+j)*64+lane], 8 KB
  const int g = blockIdx.x / 7, r = blockIdx.x % 7;
  bool is_scat;
  int ord;                                   // role-local ordinal
  if (g < 390) {                             // full groups: 3 scat + 4 gemm
    is_scat = (r < 3);
    ord = is_scat ? (g * 3 + r) : (g * 4 + (r - 3));
  } else {                                   // tail group (5 blocks): 2 + 3
    is_scat = (r < 2);
    ord = is_scat ? (1170 + r) : (1560 + (r - 2));
  }
  if (is_scat) {                             // ---- scatter (ord < 1172) ----
    int e = ord * 256 + threadIdx.x;
    if (e < NE) {
      int d = dst[e];
      int pos = atomicAdd(&cnt[d], 1);
      if (pos < CAP) col[d * CAP + pos] = src[e];  // guard: never corrupt
    }
    return;                                  // scatter blocks skip all barriers
  }
  // ---- K-split x2 gemm (ord < 1563): waves (2t+kh) own tile t's K-half kh ----
  const int wave = threadIdx.x >> 6, lane = threadIdx.x & 63;
  const int tib = wave >> 1, kh = wave & 1;
  const int tile = ord * 2 + tib;
  const bool valid = (tile < NTILES16);
  const int m = lane & 15, kg = lane >> 4;
  const int r0 = tile * 16;
  const float* xr = x + (size_t)((valid ? r0 : 0) + m) * KDIM + kh * 128 + kg * 8;
  const unsigned short* w0 = wbf + (size_t)m * KDIM + kh * 128 + kg * 8;

  #pragma unroll
  for (int j = 0; j < 8; ++j)                // 8 async 1KB stages, zero VGPRs
    gload_lds16(xr + (j >> 1) * 32 + (j & 1) * 4, &xs[wave][j][0]);
  __syncthreads();                           // vmcnt(0) drain -> xs valid

  f32x4 acc0 = {0.f, 0.f, 0.f, 0.f};
  f32x4 acc1 = {0.f, 0.f, 0.f, 0.f};
  f32x4 acc2 = {0.f, 0.f, 0.f, 0.f};
  f32x4 acc3 = {0.f, 0.f, 0.f, 0.f};
  if (valid) {
    #pragma unroll
    for (int kc = 0; kc < 4; ++kc) {
      float4 a0 = xs[wave][2 * kc][lane];    // ds_read_b128, lane's own chunk
      float4 a1 = xs[wave][2 * kc + 1][lane];
      bf16x8 af;
      af[0] = bf16_of(a0.x); af[1] = bf16_of(a0.y);
      af[2] = bf16_of(a0.z); af[3] = bf16_of(a0.w);
      af[4] = bf16_of(a1.x); af[5] = bf16_of(a1.y);
      af[6] = bf16_of(a1.z); af[7] = bf16_of(a1.w);
      bf16x8 b0 = *(const bf16x8*)(w0 + 0 * 16 * KDIM + kc * 32);
      bf16x8 b1 = *(const bf16x8*)(w0 + 1 * 16 * KDIM + kc * 32);
      bf16x8 b2 = *(const bf16x8*)(w0 + 2 * 16 * KDIM + kc * 32);
      bf16x8 b3 = *(const bf16x8*)(w0 + 3 * 16 * KDIM + kc * 32);
      acc0 = __builtin_amdgcn_mfma_f32_16x16x32_bf16(af, b0, acc0, 0, 0, 0);
      acc1 = __builtin_amdgcn_mfma_f32_16x16x32_bf16(af, b1, acc1, 0, 0, 0);
      acc2 = __builtin_amdgcn_mfma_f32_16x16x32_bf16(af, b2, acc2, 0, 0, 0);
      acc3 = __builtin_amdgcn_mfma_f32_16x16x32_bf16(af, b3, acc3, 0, 0, 0);
    }
  }
  __syncthreads();                           // ALL xs reads done (WAR vs red)
  if (valid && kh == 1) {
    #pragma unroll
    for (int j = 0; j < 4; ++j) {
      red[(tib * 16 + 0 + j) * 64 + lane]  = acc0[j];
      red[(tib * 16 + 4 + j) * 64 + lane]  = acc1[j];
      red[(tib * 16 + 8 + j) * 64 + lane]  = acc2[j];
      red[(tib * 16 + 12 + j) * 64 + lane] = acc3[j];
    }
  }
  __syncthreads();
  if (valid && kh == 0) {
    #pragma unroll
    for (int j = 0; j < 4; ++j) {
      acc0[j] += red[(tib * 16 + 0 + j) * 64 + lane];
      acc1[j] += red[(tib * 16 + 4 + j) * 64 + lane];
      acc2[j] += red[(tib * 16 + 8 + j) * 64 + lane];
      acc3[j] += red[(tib * 16 + 12 + j) * 64 + lane];
    }
    const int m4 = kg * 4;
    #pragma unroll
    for (int r2 = 0; r2 < 4; ++r2) {
      size_t rowoff = (size_t)(r0 + m4 + r2) * FDIM + m;
      yh[rowoff + 0]  = bf16_of(acc0[r2]);   // RAW Y (no dinv)
      yh[rowoff + 16] = bf16_of(acc1[r2]);
      yh[rowoff + 32] = bf16_of(acc2[r2]);
      yh[rowoff + 48] = bf16_of(acc3[r2]);
    }
  }
}

// ---------- gather hop over bf16 rows (128B): 2 nodes/wave, 32 lanes x uint ----------
// NBRNORM=1 (hop 1): u_i = dinv_i^2 * ( dinv_i*Y_i + sum_j dinv_j*Y_j )
// NBRNORM=0 (hop 2): out_i = dinv_i * ( u_i + sum_j u_j )
// fp32 accumulation; masked 4-batches (OOB multiplier/value zeroed by cndmask).
template <int OUT32, int NBRNORM>
__global__ __launch_bounds__(256) void gather_kernel(const unsigned* __restrict__ inu,
    void* __restrict__ outp, const int* __restrict__ cnt,
    const int* __restrict__ col) {
  int wave = threadIdx.x >> 6, lane = threadIdx.x & 63;
  int half = lane >> 5, hl = lane & 31;
  int node = blockIdx.x * 8 + wave * 2 + half;          // 6250*8 = 50000 exact
  int deg = cnt[node];
  int n = min(deg, CAP);
  int sbase = lane & 32;                                // half*32
  float fdeg = (float)deg + 1.0f;
  float di = rsqrtf(fdeg);
  float selfm = NBRNORM ? di : 1.0f;
  float ax, ay;
  unpack2(inu[(size_t)node * 32 + hl], ax, ay);         // self-loop
  ax *= selfm; ay *= selfm;
  float bx = 0.f, by = 0.f, cx = 0.f, cy = 0.f, dx = 0.f, dy = 0.f;
  for (int base = 0; base < n; base += 32) {
    int mB = min(32, n - base);
    int idx = 0; float dvl = 0.f;
    if (hl < mB) {
      idx = col[node * CAP + base + hl];
      if (NBRNORM) dvl = rsqrtf((float)cnt[idx] + 1.0f);
    }
    for (int j = 0; j < mB; j += 4) {
      int c0 = __shfl(idx, sbase + j + 0);
      int c1 = __shfl(idx, sbase + j + 1);
      int c2 = __shfl(idx, sbase + j + 2);
      int c3 = __shfl(idx, sbase + j + 3);
      unsigned u0 = inu[(size_t)c0 * 32 + hl];
      unsigned u1 = inu[(size_t)c1 * 32 + hl];
      unsigned u2 = inu[(size_t)c2 * 32 + hl];
      unsigned u3 = inu[(size_t)c3 * 32 + hl];
      float lx, hy;
      if (NBRNORM) {
        float f0 = __shfl(dvl, sbase + j + 0);
        float f1 = __shfl(dvl, sbase + j + 1);
        float f2 = __shfl(dvl, sbase + j + 2);
        float f3 = __shfl(dvl, sbase + j + 3);
        f1 = (j + 1 < mB) ? f1 : 0.f;                   // mask the multiplier
        f2 = (j + 2 < mB) ? f2 : 0.f;
        f3 = (j + 3 < mB) ? f3 : 0.f;
        unpack2(u0, lx, hy); ax = fmaf(lx, f0, ax); ay = fmaf(hy, f0, ay);
        unpack2(u1, lx, hy); bx = fmaf(lx, f1, bx); by = fmaf(hy, f1, by);
        unpack2(u2, lx, hy); cx = fmaf(lx, f2, cx); cy = fmaf(hy, f2, cy);
        unpack2(u3, lx, hy); dx = fmaf(lx, f3, dx); dy = fmaf(hy, f3, dy);
      } else {
        u1 = (j + 1 < mB) ? u1 : 0u;                    // mask the value
        u2 = (j + 2 < mB) ? u2 : 0u;
        u3 = (j + 3 < mB) ? u3 : 0u;
        unpack2(u0, lx, hy); ax += lx; ay += hy;
        unpack2(u1, lx, hy); bx += lx; by += hy;
        unpack2(u2, lx, hy); cx += lx; cy += hy;
        unpack2(u3, lx, hy); dx += lx; dy += hy;
      }
    }
  }
  float s = NBRNORM ? (1.0f / fdeg) : di;               // dinv^2 : dinv
  float rx = (ax + bx + cx + dx) * s;
  float ry = (ay + by + cy + dy) * s;
  if (OUT32) {
    float2 r; r.x = rx; r.y = ry;
    ((float2*)outp)[(size_t)node * 32 + hl] = r;        // fp32 row = 32 float2
  } else {
    ((unsigned*)outp)[(size_t)node * 32 + hl] = pack2(rx, ry);  // bf16 row
  }
}

extern "C" void kernel_launch(void* const* d_in, const int* in_sizes, int n_in,
                              void* d_out, int out_size, void* d_ws, size_t ws_size,
                              hipStream_t stream) {
  const float* x = (const float*)d_in[0];    // [NN, 256]
  const int* ei  = (const int*)d_in[1];      // [2, NE]
  const float* W = (const float*)d_in[2];    // [64, 256]
  float* out     = (float*)d_out;            // [NN, 64]
  const int* src = ei;
  const int* dst = ei + NE;

  // ws (4B units): cnt[NN] | col[NN*CAP] | yh[NN*32] | zh[NN*32] | wbf[8192]
  size_t o_cnt = 0;
  size_t o_col = o_cnt + NN;
  size_t o_yh  = o_col + (size_t)NN * CAP;
  size_t o_zh  = o_yh + (size_t)NN * (FDIM / 2);
  size_t o_wbf = o_zh + (size_t)NN * (FDIM / 2);
  size_t need  = (o_wbf + 8192) * 4;         // ~22.8 MB
  if (ws_size < need || d_ws == nullptr) return;  // fail loudly, never OOB

  int* cnt           = (int*)d_ws + o_cnt;
  int* col           = (int*)d_ws + o_col;
  unsigned short* yh = (unsigned short*)((float*)d_ws + o_yh);
  unsigned short* zh = (unsigned short*)((float*)d_ws + o_zh);
  unsigned short* wbf= (unsigned short*)((float*)d_ws + o_wbf);

  // 1. zero cnt (200KB) + W->bf16
  init_kernel<<<260, 256, 0, stream>>>(cnt, W, wbf);
  // 2. fused scatter||gemm, interleaved 3:4, 32KB LDS (5 blocks/CU)
  fused_kernel<<<FUSE_BLKS, 256, 0, stream>>>(src, dst, cnt, col, x, wbf, yh);
  // 3. hop 1: zh = bf16( dinv^2 * (dinv*Y_self + sum dinv_j*Y_j) )
  gather_kernel<0, 1><<<NN / 8, 256, 0, stream>>>((const unsigned*)yh, zh, cnt, col);
  // 4. hop 2: out = dinv * (A+I) zh
  gather_kernel<1, 0><<<NN / 8, 256, 0, stream>>>((const unsigned*)zh, out, cnt, col);
}

// Round 33
// 57.405 us; speedup vs baseline: 1.1464x; 1.1464x over previous
//
#include <hip/hip_runtime.h>

#define NN 50000
#define NE 300000
#define KDIM 256
#define FDIM 64
#define CAP 48              // max degree capacity; P(deg>47)~1e-30 for multinomial(6)
#define NTILES16 (NN / 16)  // 3125 row-tiles for MFMA gemm
#define SCAT_BLKS ((NE + 255) / 256)          // 1172
#define GEMM_BLKS ((NTILES16 + 1) / 2)        // 1563
#define FUSE_BLKS (SCAT_BLKS + GEMM_BLKS)     // 2735 = 7*390 + 5

typedef __attribute__((ext_vector_type(8))) short bf16x8;
typedef __attribute__((ext_vector_type(4))) float f32x4;

static __device__ __forceinline__ unsigned short bf16_of(float f) {
  union { float f; unsigned u; } v; v.f = f;
  unsigned r = (v.u + 0x7fffu + ((v.u >> 16) & 1u)) >> 16;  // RTNE
  return (unsigned short)r;
}
static __device__ __forceinline__ void unpack2(unsigned u, float& lo, float& hi) {
  union { unsigned u; float f; } a, b;
  a.u = u << 16; b.u = u & 0xffff0000u;
  lo = a.f; hi = b.f;
}
static __device__ __forceinline__ unsigned pack2(float lo, float hi) {
  return (unsigned)bf16_of(lo) | ((unsigned)bf16_of(hi) << 16);
}

// async global->LDS, 16B per lane: LDS dest = wave-uniform base + lane*16.
static __device__ __forceinline__ void gload_lds16(const float* g, void* l) {
  __builtin_amdgcn_global_load_lds(
      (const __attribute__((address_space(1))) void*)g,
      (__attribute__((address_space(3))) void*)l, 16, 0, 0);
}

// ---------- init: zero cnt (blocks 0..195) + W->bf16 SWIZZLED (196..259) ----------
// wbf layout (R33): flat short index
//   kh*8192 + (kc*4+kg)*512 + n*128 + m*8 + j
// holds W[f=n*16+m][k=kh*128+kc*32+kg*8+j]. A B-fragment load (fixed n,kc)
// then reads lane-contiguous 256B chunks (8 fully-used lines/instr instead of
// 64 scattered lines) -> kills the 8x L2 gather amplification.
__global__ __launch_bounds__(256) void init_kernel(int* __restrict__ cnt,
    const float* __restrict__ W, unsigned short* __restrict__ wbf) {
  int b = blockIdx.x, t = threadIdx.x;
  if (b < 196) {
    int i = b * 256 + t;
    if (i < NN) cnt[i] = 0;
  } else {
    int i = (b - 196) * 256 + t;    // 0..16383
    int kh = i >> 13;
    int r  = i & 8191;
    int kcgn = r >> 7;              // (kc*4+kg)*4 + n, 0..63
    int m8j  = r & 127;
    int m = m8j >> 3, j = m8j & 7;
    int n  = kcgn & 3;
    int kcg = kcgn >> 2;            // kc*4+kg
    int kc = kcg >> 2, kg = kcg & 3;
    int f = n * 16 + m;
    int k = kh * 128 + kc * 32 + kg * 8 + j;
    wbf[i] = bf16_of(W[f * KDIM + k]);
  }
}

// ---------- fused: scatter || gemm, INTERLEAVED roles, swizzled-B gemm ----------
// R30: interleave {3 scat, 4 gemm}/7 -> co-residency. R32: red aliases xs
// (32KB LDS). R33: B-fragments read from pre-swizzled wbf (lane-contiguous).
// gemm emits RAW Y = x@W^T (bf16); dinv deferred to hops:
//   out = D^-1/2 (A+I) D^-1 (A+I) D^-1/2 Y.
// C/D: col=lane&15, row=(lane>>4)*4+reg (HW-verified m89).
__global__ __launch_bounds__(256) void fused_kernel(
    const int* __restrict__ src, const int* __restrict__ dst,
    int* __restrict__ cnt, int* __restrict__ col,
    const float* __restrict__ x, const unsigned short* __restrict__ wbf,
    unsigned short* __restrict__ yh) {
  __shared__ float4 xs[4][8][64];            // 32 KB; red aliases this after use
  float* red = (float*)&xs[0][0][0];         // red[(tib*16+j)*64+lane], 8 KB
  const int g = blockIdx.x / 7, r = blockIdx.x % 7;
  bool is_scat;
  int ord;                                   // role-local ordinal
  if (g < 390) {                             // full groups: 3 scat + 4 gemm
    is_scat = (r < 3);
    ord = is_scat ? (g * 3 + r) : (g * 4 + (r - 3));
  } else {                                   // tail group (5 blocks): 2 + 3
    is_scat = (r < 2);
    ord = is_scat ? (1170 + r) : (1560 + (r - 2));
  }
  if (is_scat) {                             // ---- scatter (ord < 1172) ----
    int e = ord * 256 + threadIdx.x;
    if (e < NE) {
      int d = dst[e];
      int pos = atomicAdd(&cnt[d], 1);
      if (pos < CAP) col[d * CAP + pos] = src[e];  // guard: never corrupt
    }
    return;                                  // scatter blocks skip all barriers
  }
  // ---- K-split x2 gemm (ord < 1563): waves (2t+kh) own tile t's K-half kh ----
  const int wave = threadIdx.x >> 6, lane = threadIdx.x & 63;
  const int tib = wave >> 1, kh = wave & 1;
  const int tile = ord * 2 + tib;
  const bool valid = (tile < NTILES16);
  const int m = lane & 15, kg = lane >> 4;
  const int r0 = tile * 16;
  const float* xr = x + (size_t)((valid ? r0 : 0) + m) * KDIM + kh * 128 + kg * 8;
  // swizzled B base for this lane/K-half: + kc*2048 + n*128 per fragment
  const unsigned short* wk = wbf + kh * 8192 + kg * 512 + m * 8;

  #pragma unroll
  for (int j = 0; j < 8; ++j)                // 8 async 1KB stages, zero VGPRs
    gload_lds16(xr + (j >> 1) * 32 + (j & 1) * 4, &xs[wave][j][0]);
  __syncthreads();                           // vmcnt(0) drain -> xs valid

  f32x4 acc0 = {0.f, 0.f, 0.f, 0.f};
  f32x4 acc1 = {0.f, 0.f, 0.f, 0.f};
  f32x4 acc2 = {0.f, 0.f, 0.f, 0.f};
  f32x4 acc3 = {0.f, 0.f, 0.f, 0.f};
  if (valid) {
    #pragma unroll
    for (int kc = 0; kc < 4; ++kc) {
      float4 a0 = xs[wave][2 * kc][lane];    // ds_read_b128, lane's own chunk
      float4 a1 = xs[wave][2 * kc + 1][lane];
      bf16x8 af;
      af[0] = bf16_of(a0.x); af[1] = bf16_of(a0.y);
      af[2] = bf16_of(a0.z); af[3] = bf16_of(a0.w);
      af[4] = bf16_of(a1.x); af[5] = bf16_of(a1.y);
      af[6] = bf16_of(a1.z); af[7] = bf16_of(a1.w);
      const unsigned short* wc = wk + kc * 2048;
      bf16x8 b0 = *(const bf16x8*)(wc + 0 * 128);   // lane-contiguous 256B chunks
      bf16x8 b1 = *(const bf16x8*)(wc + 1 * 128);
      bf16x8 b2 = *(const bf16x8*)(wc + 2 * 128);
      bf16x8 b3 = *(const bf16x8*)(wc + 3 * 128);
      acc0 = __builtin_amdgcn_mfma_f32_16x16x32_bf16(af, b0, acc0, 0, 0, 0);
      acc1 = __builtin_amdgcn_mfma_f32_16x16x32_bf16(af, b1, acc1, 0, 0, 0);
      acc2 = __builtin_amdgcn_mfma_f32_16x16x32_bf16(af, b2, acc2, 0, 0, 0);
      acc3 = __builtin_amdgcn_mfma_f32_16x16x32_bf16(af, b3, acc3, 0, 0, 0);
    }
  }
  __syncthreads();                           // ALL xs reads done (WAR vs red)
  if (valid && kh == 1) {
    #pragma unroll
    for (int j = 0; j < 4; ++j) {
      red[(tib * 16 + 0 + j) * 64 + lane]  = acc0[j];
      red[(tib * 16 + 4 + j) * 64 + lane]  = acc1[j];
      red[(tib * 16 + 8 + j) * 64 + lane]  = acc2[j];
      red[(tib * 16 + 12 + j) * 64 + lane] = acc3[j];
    }
  }
  __syncthreads();
  if (valid && kh == 0) {
    #pragma unroll
    for (int j = 0; j < 4; ++j) {
      acc0[j] += red[(tib * 16 + 0 + j) * 64 + lane];
      acc1[j] += red[(tib * 16 + 4 + j) * 64 + lane];
      acc2[j] += red[(tib * 16 + 8 + j) * 64 + lane];
      acc3[j] += red[(tib * 16 + 12 + j) * 64 + lane];
    }
    const int m4 = kg * 4;
    #pragma unroll
    for (int r2 = 0; r2 < 4; ++r2) {
      size_t rowoff = (size_t)(r0 + m4 + r2) * FDIM + m;
      yh[rowoff + 0]  = bf16_of(acc0[r2]);   // RAW Y (no dinv)
      yh[rowoff + 16] = bf16_of(acc1[r2]);
      yh[rowoff + 32] = bf16_of(acc2[r2]);
      yh[rowoff + 48] = bf16_of(acc3[r2]);
    }
  }
}

// ---------- gather hop over bf16 rows (128B): 2 nodes/wave, 32 lanes x uint ----------
// NBRNORM=1 (hop 1): u_i = dinv_i^2 * ( dinv_i*Y_i + sum_j dinv_j*Y_j )
// NBRNORM=0 (hop 2): out_i = dinv_i * ( u_i + sum_j u_j )
// fp32 accumulation; masked 4-batches (OOB multiplier/value zeroed by cndmask).
template <int OUT32, int NBRNORM>
__global__ __launch_bounds__(256) void gather_kernel(const unsigned* __restrict__ inu,
    void* __restrict__ outp, const int* __restrict__ cnt,
    const int* __restrict__ col) {
  int wave = threadIdx.x >> 6, lane = threadIdx.x & 63;
  int half = lane >> 5, hl = lane & 31;
  int node = blockIdx.x * 8 + wave * 2 + half;          // 6250*8 = 50000 exact
  int deg = cnt[node];
  int n = min(deg, CAP);
  int sbase = lane & 32;                                // half*32
  float fdeg = (float)deg + 1.0f;
  float di = rsqrtf(fdeg);
  float selfm = NBRNORM ? di : 1.0f;
  float ax, ay;
  unpack2(inu[(size_t)node * 32 + hl], ax, ay);         // self-loop
  ax *= selfm; ay *= selfm;
  float bx = 0.f, by = 0.f, cx = 0.f, cy = 0.f, dx = 0.f, dy = 0.f;
  for (int base = 0; base < n; base += 32) {
    int mB = min(32, n - base);
    int idx = 0; float dvl = 0.f;
    if (hl < mB) {
      idx = col[node * CAP + base + hl];
      if (NBRNORM) dvl = rsqrtf((float)cnt[idx] + 1.0f);
    }
    for (int j = 0; j < mB; j += 4) {
      int c0 = __shfl(idx, sbase + j + 0);
      int c1 = __shfl(idx, sbase + j + 1);
      int c2 = __shfl(idx, sbase + j + 2);
      int c3 = __shfl(idx, sbase + j + 3);
      unsigned u0 = inu[(size_t)c0 * 32 + hl];
      unsigned u1 = inu[(size_t)c1 * 32 + hl];
      unsigned u2 = inu[(size_t)c2 * 32 + hl];
      unsigned u3 = inu[(size_t)c3 * 32 + hl];
      float lx, hy;
      if (NBRNORM) {
        float f0 = __shfl(dvl, sbase + j + 0);
        float f1 = __shfl(dvl, sbase + j + 1);
        float f2 = __shfl(dvl, sbase + j + 2);
        float f3 = __shfl(dvl, sbase + j + 3);
        f1 = (j + 1 < mB) ? f1 : 0.f;                   // mask the multiplier
        f2 = (j + 2 < mB) ? f2 : 0.f;
        f3 = (j + 3 < mB) ? f3 : 0.f;
        unpack2(u0, lx, hy); ax = fmaf(lx, f0, ax); ay = fmaf(hy, f0, ay);
        unpack2(u1, lx, hy); bx = fmaf(lx, f1, bx); by = fmaf(hy, f1, by);
        unpack2(u2, lx, hy); cx = fmaf(lx, f2, cx); cy = fmaf(hy, f2, cy);
        unpack2(u3, lx, hy); dx = fmaf(lx, f3, dx); dy = fmaf(hy, f3, dy);
      } else {
        u1 = (j + 1 < mB) ? u1 : 0u;                    // mask the value
        u2 = (j + 2 < mB) ? u2 : 0u;
        u3 = (j + 3 < mB) ? u3 : 0u;
        unpack2(u0, lx, hy); ax += lx; ay += hy;
        unpack2(u1, lx, hy); bx += lx; by += hy;
        unpack2(u2, lx, hy); cx += lx; cy += hy;
        unpack2(u3, lx, hy); dx += lx; dy += hy;
      }
    }
  }
  float s = NBRNORM ? (1.0f / fdeg) : di;               // dinv^2 : dinv
  float rx = (ax + bx + cx + dx) * s;
  float ry = (ay + by + cy + dy) * s;
  if (OUT32) {
    float2 r; r.x = rx; r.y = ry;
    ((float2*)outp)[(size_t)node * 32 + hl] = r;        // fp32 row = 32 float2
  } else {
    ((unsigned*)outp)[(size_t)node * 32 + hl] = pack2(rx, ry);  // bf16 row
  }
}

extern "C" void kernel_launch(void* const* d_in, const int* in_sizes, int n_in,
                              void* d_out, int out_size, void* d_ws, size_t ws_size,
                              hipStream_t stream) {
  const float* x = (const float*)d_in[0];    // [NN, 256]
  const int* ei  = (const int*)d_in[1];      // [2, NE]
  const float* W = (const float*)d_in[2];    // [64, 256]
  float* out     = (float*)d_out;            // [NN, 64]
  const int* src = ei;
  const int* dst = ei + NE;

  // ws (4B units): cnt[NN] | col[NN*CAP] | yh[NN*32] | zh[NN*32] | wbf[8192]
  size_t o_cnt = 0;
  size_t o_col = o_cnt + NN;
  size_t o_yh  = o_col + (size_t)NN * CAP;
  size_t o_zh  = o_yh + (size_t)NN * (FDIM / 2);
  size_t o_wbf = o_zh + (size_t)NN * (FDIM / 2);
  size_t need  = (o_wbf + 8192) * 4;         // ~22.8 MB
  if (ws_size < need || d_ws == nullptr) return;  // fail loudly, never OOB

  int* cnt           = (int*)d_ws + o_cnt;
  int* col           = (int*)d_ws + o_col;
  unsigned short* yh = (unsigned short*)((float*)d_ws + o_yh);
  unsigned short* zh = (unsigned short*)((float*)d_ws + o_zh);
  unsigned short* wbf= (unsigned short*)((float*)d_ws + o_wbf);

  // 1. zero cnt (200KB) + W->bf16 (fragment-swizzled layout)
  init_kernel<<<260, 256, 0, stream>>>(cnt, W, wbf);
  // 2. fused scatter||gemm, interleaved 3:4, swizzled-B fragment loads
  fused_kernel<<<FUSE_BLKS, 256, 0, stream>>>(src, dst, cnt, col, x, wbf, yh);
  // 3. hop 1: zh = bf16( dinv^2 * (dinv*Y_self + sum dinv_j*Y_j) )
  gather_kernel<0, 1><<<NN / 8, 256, 0, stream>>>((const unsigned*)yh, zh, cnt, col);
  // 4. hop 2: out = dinv * (A+I) zh
  gather_kernel<1, 0><<<NN / 8, 256, 0, stream>>>((const unsigned*)zh, out, cnt, col);
}

// Round 34
// 56.080 us; speedup vs baseline: 1.1734x; 1.0236x over previous
//
#include <hip/hip_runtime.h>

#define NN 50000
#define NE 300000
#define KDIM 256
#define FDIM 64
#define CAP 48              // max degree capacity; P(deg>47)~1e-30 for multinomial(6)
#define NTILES16 (NN / 16)  // 3125 row-tiles for MFMA gemm
#define SCAT_BLKS ((NE + 255) / 256)          // 1172
#define GEMM_BLKS ((NTILES16 + 1) / 2)        // 1563
#define FUSE_BLKS (SCAT_BLKS + GEMM_BLKS)     // 2735 = 7*390 + 5

typedef __attribute__((ext_vector_type(8))) short bf16x8;
typedef __attribute__((ext_vector_type(4))) float f32x4;

static __device__ __forceinline__ unsigned short bf16_of(float f) {
  union { float f; unsigned u; } v; v.f = f;
  unsigned r = (v.u + 0x7fffu + ((v.u >> 16) & 1u)) >> 16;  // RTNE
  return (unsigned short)r;
}
static __device__ __forceinline__ void unpack2(unsigned u, float& lo, float& hi) {
  union { unsigned u; float f; } a, b;
  a.u = u << 16; b.u = u & 0xffff0000u;
  lo = a.f; hi = b.f;
}
static __device__ __forceinline__ unsigned pack2(float lo, float hi) {
  return (unsigned)bf16_of(lo) | ((unsigned)bf16_of(hi) << 16);
}

// async global->LDS, 16B per lane: LDS dest = wave-uniform base + lane*16.
static __device__ __forceinline__ void gload_lds16(const float* g, void* l) {
  __builtin_amdgcn_global_load_lds(
      (const __attribute__((address_space(1))) void*)g,
      (__attribute__((address_space(3))) void*)l, 16, 0, 0);
}

// ---------- init: zero cnt (blocks 0..195) + W->bf16 SWIZZLED (196..259) ----------
// wbf layout (R33): flat short index kh*8192 + (kc*4+kg)*512 + n*128 + m*8 + j
// holds W[f=n*16+m][k=kh*128+kc*32+kg*8+j]. B-fragment loads are then
// lane-contiguous (8 fully-used lines/instr vs 64 scattered) -> R33: -8us.
__global__ __launch_bounds__(256) void init_kernel(int* __restrict__ cnt,
    const float* __restrict__ W, unsigned short* __restrict__ wbf) {
  int b = blockIdx.x, t = threadIdx.x;
  if (b < 196) {
    int i = b * 256 + t;
    if (i < NN) cnt[i] = 0;
  } else {
    int i = (b - 196) * 256 + t;    // 0..16383
    int kh = i >> 13;
    int r  = i & 8191;
    int kcgn = r >> 7;              // (kc*4+kg)*4 + n, 0..63
    int m8j  = r & 127;
    int m = m8j >> 3, j = m8j & 7;
    int n  = kcgn & 3;
    int kcg = kcgn >> 2;            // kc*4+kg
    int kc = kcg >> 2, kg = kcg & 3;
    int f = n * 16 + m;
    int k = kh * 128 + kc * 32 + kg * 8 + j;
    wbf[i] = bf16_of(W[f * KDIM + k]);
  }
}

// ---------- fused: scatter || gemm, INTERLEAVED roles, swizzled-B gemm ----------
// R30: interleave {3 scat, 4 gemm}/7 -> co-residency. R32: red aliases xs
// (32KB LDS). R33: B pre-swizzled (lane-contiguous fragments).
// gemm emits RAW Y = x@W^T (bf16); dinv deferred to hops:
//   out = D^-1/2 (A+I) D^-1 (A+I) D^-1/2 Y.
// C/D: col=lane&15, row=(lane>>4)*4+reg (HW-verified m89).
__global__ __launch_bounds__(256) void fused_kernel(
    const int* __restrict__ src, const int* __restrict__ dst,
    int* __restrict__ cnt, int* __restrict__ col,
    const float* __restrict__ x, const unsigned short* __restrict__ wbf,
    unsigned short* __restrict__ yh) {
  __shared__ float4 xs[4][8][64];            // 32 KB; red aliases this after use
  float* red = (float*)&xs[0][0][0];         // red[(tib*16+j)*64+lane], 8 KB
  const int g = blockIdx.x / 7, r = blockIdx.x % 7;
  bool is_scat;
  int ord;                                   // role-local ordinal
  if (g < 390) {                             // full groups: 3 scat + 4 gemm
    is_scat = (r < 3);
    ord = is_scat ? (g * 3 + r) : (g * 4 + (r - 3));
  } else {                                   // tail group (5 blocks): 2 + 3
    is_scat = (r < 2);
    ord = is_scat ? (1170 + r) : (1560 + (r - 2));
  }
  if (is_scat) {                             // ---- scatter (ord < 1172) ----
    int e = ord * 256 + threadIdx.x;
    if (e < NE) {
      int d = dst[e];
      int pos = atomicAdd(&cnt[d], 1);
      if (pos < CAP) col[d * CAP + pos] = src[e];  // guard: never corrupt
    }
    return;                                  // scatter blocks skip all barriers
  }
  // ---- K-split x2 gemm (ord < 1563): waves (2t+kh) own tile t's K-half kh ----
  const int wave = threadIdx.x >> 6, lane = threadIdx.x & 63;
  const int tib = wave >> 1, kh = wave & 1;
  const int tile = ord * 2 + tib;
  const bool valid = (tile < NTILES16);
  const int m = lane & 15, kg = lane >> 4;
  const int r0 = tile * 16;
  const float* xr = x + (size_t)((valid ? r0 : 0) + m) * KDIM + kh * 128 + kg * 8;
  const unsigned short* wk = wbf + kh * 8192 + kg * 512 + m * 8;

  #pragma unroll
  for (int j = 0; j < 8; ++j)                // 8 async 1KB stages, zero VGPRs
    gload_lds16(xr + (j >> 1) * 32 + (j & 1) * 4, &xs[wave][j][0]);
  __syncthreads();                           // vmcnt(0) drain -> xs valid

  f32x4 acc0 = {0.f, 0.f, 0.f, 0.f};
  f32x4 acc1 = {0.f, 0.f, 0.f, 0.f};
  f32x4 acc2 = {0.f, 0.f, 0.f, 0.f};
  f32x4 acc3 = {0.f, 0.f, 0.f, 0.f};
  if (valid) {
    #pragma unroll
    for (int kc = 0; kc < 4; ++kc) {
      float4 a0 = xs[wave][2 * kc][lane];    // ds_read_b128, lane's own chunk
      float4 a1 = xs[wave][2 * kc + 1][lane];
      bf16x8 af;
      af[0] = bf16_of(a0.x); af[1] = bf16_of(a0.y);
      af[2] = bf16_of(a0.z); af[3] = bf16_of(a0.w);
      af[4] = bf16_of(a1.x); af[5] = bf16_of(a1.y);
      af[6] = bf16_of(a1.z); af[7] = bf16_of(a1.w);
      const unsigned short* wc = wk + kc * 2048;
      bf16x8 b0 = *(const bf16x8*)(wc + 0 * 128);   // lane-contiguous 256B chunks
      bf16x8 b1 = *(const bf16x8*)(wc + 1 * 128);
      bf16x8 b2 = *(const bf16x8*)(wc + 2 * 128);
      bf16x8 b3 = *(const bf16x8*)(wc + 3 * 128);
      acc0 = __builtin_amdgcn_mfma_f32_16x16x32_bf16(af, b0, acc0, 0, 0, 0);
      acc1 = __builtin_amdgcn_mfma_f32_16x16x32_bf16(af, b1, acc1, 0, 0, 0);
      acc2 = __builtin_amdgcn_mfma_f32_16x16x32_bf16(af, b2, acc2, 0, 0, 0);
      acc3 = __builtin_amdgcn_mfma_f32_16x16x32_bf16(af, b3, acc3, 0, 0, 0);
    }
  }
  __syncthreads();                           // ALL xs reads done (WAR vs red)
  if (valid && kh == 1) {
    #pragma unroll
    for (int j = 0; j < 4; ++j) {
      red[(tib * 16 + 0 + j) * 64 + lane]  = acc0[j];
      red[(tib * 16 + 4 + j) * 64 + lane]  = acc1[j];
      red[(tib * 16 + 8 + j) * 64 + lane]  = acc2[j];
      red[(tib * 16 + 12 + j) * 64 + lane] = acc3[j];
    }
  }
  __syncthreads();
  if (valid && kh == 0) {
    #pragma unroll
    for (int j = 0; j < 4; ++j) {
      acc0[j] += red[(tib * 16 + 0 + j) * 64 + lane];
      acc1[j] += red[(tib * 16 + 4 + j) * 64 + lane];
      acc2[j] += red[(tib * 16 + 8 + j) * 64 + lane];
      acc3[j] += red[(tib * 16 + 12 + j) * 64 + lane];
    }
    const int m4 = kg * 4;
    #pragma unroll
    for (int r2 = 0; r2 < 4; ++r2) {
      size_t rowoff = (size_t)(r0 + m4 + r2) * FDIM + m;
      yh[rowoff + 0]  = bf16_of(acc0[r2]);   // RAW Y (no dinv)
      yh[rowoff + 16] = bf16_of(acc1[r2]);
      yh[rowoff + 32] = bf16_of(acc2[r2]);
      yh[rowoff + 48] = bf16_of(acc3[r2]);
    }
  }
}

// ---------- gather hop over bf16 rows (128B): 2 nodes/wave, 32 lanes x uint ----------
// R34: j-loop widened to 8 loads in flight (was 4) — avg deg 6 now pays ONE
// latency exposure instead of two serial 4-batches.
// NBRNORM=1 (hop 1): u_i = dinv_i^2 * ( dinv_i*Y_i + sum_j dinv_j*Y_j )
// NBRNORM=0 (hop 2): out_i = dinv_i * ( u_i + sum_j u_j )
// fp32 accumulation; masked batches (OOB multiplier/value zeroed by cndmask).
template <int OUT32, int NBRNORM>
__global__ __launch_bounds__(256) void gather_kernel(const unsigned* __restrict__ inu,
    void* __restrict__ outp, const int* __restrict__ cnt,
    const int* __restrict__ col) {
  int wave = threadIdx.x >> 6, lane = threadIdx.x & 63;
  int half = lane >> 5, hl = lane & 31;
  int node = blockIdx.x * 8 + wave * 2 + half;          // 6250*8 = 50000 exact
  int deg = cnt[node];
  int n = min(deg, CAP);
  int sbase = lane & 32;                                // half*32
  float fdeg = (float)deg + 1.0f;
  float di = rsqrtf(fdeg);
  float selfm = NBRNORM ? di : 1.0f;
  float ax, ay;
  unpack2(inu[(size_t)node * 32 + hl], ax, ay);         // self-loop
  ax *= selfm; ay *= selfm;
  float bx = 0.f, by = 0.f, cx = 0.f, cy = 0.f, dx = 0.f, dy = 0.f;
  for (int base = 0; base < n; base += 32) {
    int mB = min(32, n - base);
    int idx = 0; float dvl = 0.f;
    if (hl < mB) {
      idx = col[node * CAP + base + hl];
      if (NBRNORM) dvl = rsqrtf((float)cnt[idx] + 1.0f);
    }
    for (int j = 0; j < mB; j += 8) {                   // 8-deep load batches
      int c0 = __shfl(idx, sbase + j + 0);
      int c1 = __shfl(idx, sbase + j + 1);
      int c2 = __shfl(idx, sbase + j + 2);
      int c3 = __shfl(idx, sbase + j + 3);
      int c4 = __shfl(idx, sbase + j + 4);
      int c5 = __shfl(idx, sbase + j + 5);
      int c6 = __shfl(idx, sbase + j + 6);
      int c7 = __shfl(idx, sbase + j + 7);
      unsigned u0 = inu[(size_t)c0 * 32 + hl];
      unsigned u1 = inu[(size_t)c1 * 32 + hl];
      unsigned u2 = inu[(size_t)c2 * 32 + hl];
      unsigned u3 = inu[(size_t)c3 * 32 + hl];
      unsigned u4 = inu[(size_t)c4 * 32 + hl];
      unsigned u5 = inu[(size_t)c5 * 32 + hl];
      unsigned u6 = inu[(size_t)c6 * 32 + hl];
      unsigned u7 = inu[(size_t)c7 * 32 + hl];
      float lx, hy;
      if (NBRNORM) {
        float f0 = __shfl(dvl, sbase + j + 0);
        float f1 = __shfl(dvl, sbase + j + 1);
        float f2 = __shfl(dvl, sbase + j + 2);
        float f3 = __shfl(dvl, sbase + j + 3);
        float f4 = __shfl(dvl, sbase + j + 4);
        float f5 = __shfl(dvl, sbase + j + 5);
        float f6 = __shfl(dvl, sbase + j + 6);
        float f7 = __shfl(dvl, sbase + j + 7);
        f1 = (j + 1 < mB) ? f1 : 0.f;                   // mask the multiplier
        f2 = (j + 2 < mB) ? f2 : 0.f;
        f3 = (j + 3 < mB) ? f3 : 0.f;
        f4 = (j + 4 < mB) ? f4 : 0.f;
        f5 = (j + 5 < mB) ? f5 : 0.f;
        f6 = (j + 6 < mB) ? f6 : 0.f;
        f7 = (j + 7 < mB) ? f7 : 0.f;
        unpack2(u0, lx, hy); ax = fmaf(lx, f0, ax); ay = fmaf(hy, f0, ay);
        unpack2(u1, lx, hy); bx = fmaf(lx, f1, bx); by = fmaf(hy, f1, by);
        unpack2(u2, lx, hy); cx = fmaf(lx, f2, cx); cy = fmaf(hy, f2, cy);
        unpack2(u3, lx, hy); dx = fmaf(lx, f3, dx); dy = fmaf(hy, f3, dy);
        unpack2(u4, lx, hy); ax = fmaf(lx, f4, ax); ay = fmaf(hy, f4, ay);
        unpack2(u5, lx, hy); bx = fmaf(lx, f5, bx); by = fmaf(hy, f5, by);
        unpack2(u6, lx, hy); cx = fmaf(lx, f6, cx); cy = fmaf(hy, f6, cy);
        unpack2(u7, lx, hy); dx = fmaf(lx, f7, dx); dy = fmaf(hy, f7, dy);
      } else {
        u1 = (j + 1 < mB) ? u1 : 0u;                    // mask the value
        u2 = (j + 2 < mB) ? u2 : 0u;
        u3 = (j + 3 < mB) ? u3 : 0u;
        u4 = (j + 4 < mB) ? u4 : 0u;
        u5 = (j + 5 < mB) ? u5 : 0u;
        u6 = (j + 6 < mB) ? u6 : 0u;
        u7 = (j + 7 < mB) ? u7 : 0u;
        unpack2(u0, lx, hy); ax += lx; ay += hy;
        unpack2(u1, lx, hy); bx += lx; by += hy;
        unpack2(u2, lx, hy); cx += lx; cy += hy;
        unpack2(u3, lx, hy); dx += lx; dy += hy;
        unpack2(u4, lx, hy); ax += lx; ay += hy;
        unpack2(u5, lx, hy); bx += lx; by += hy;
        unpack2(u6, lx, hy); cx += lx; cy += hy;
        unpack2(u7, lx, hy); dx += lx; dy += hy;
      }
    }
  }
  float s = NBRNORM ? (1.0f / fdeg) : di;               // dinv^2 : dinv
  float rx = (ax + bx + cx + dx) * s;
  float ry = (ay + by + cy + dy) * s;
  if (OUT32) {
    float2 r; r.x = rx; r.y = ry;
    ((float2*)outp)[(size_t)node * 32 + hl] = r;        // fp32 row = 32 float2
  } else {
    ((unsigned*)outp)[(size_t)node * 32 + hl] = pack2(rx, ry);  // bf16 row
  }
}

extern "C" void kernel_launch(void* const* d_in, const int* in_sizes, int n_in,
                              void* d_out, int out_size, void* d_ws, size_t ws_size,
                              hipStream_t stream) {
  const float* x = (const float*)d_in[0];    // [NN, 256]
  const int* ei  = (const int*)d_in[1];      // [2, NE]
  const float* W = (const float*)d_in[2];    // [64, 256]
  float* out     = (float*)d_out;            // [NN, 64]
  const int* src = ei;
  const int* dst = ei + NE;

  // ws (4B units): cnt[NN] | col[NN*CAP] | yh[NN*32] | zh[NN*32] | wbf[8192]
  size_t o_cnt = 0;
  size_t o_col = o_cnt + NN;
  size_t o_yh  = o_col + (size_t)NN * CAP;
  size_t o_zh  = o_yh + (size_t)NN * (FDIM / 2);
  size_t o_wbf = o_zh + (size_t)NN * (FDIM / 2);
  size_t need  = (o_wbf + 8192) * 4;         // ~22.8 MB
  if (ws_size < need || d_ws == nullptr) return;  // fail loudly, never OOB

  int* cnt           = (int*)d_ws + o_cnt;
  int* col           = (int*)d_ws + o_col;
  unsigned short* yh = (unsigned short*)((float*)d_ws + o_yh);
  unsigned short* zh = (unsigned short*)((float*)d_ws + o_zh);
  unsigned short* wbf= (unsigned short*)((float*)d_ws + o_wbf);

  // 1. zero cnt (200KB) + W->bf16 (fragment-swizzled layout)
  init_kernel<<<260, 256, 0, stream>>>(cnt, W, wbf);
  // 2. fused scatter||gemm, interleaved 3:4, swizzled-B fragment loads
  fused_kernel<<<FUSE_BLKS, 256, 0, stream>>>(src, dst, cnt, col, x, wbf, yh);
  // 3. hop 1: zh = bf16( dinv^2 * (dinv*Y_self + sum dinv_j*Y_j) )
  gather_kernel<0, 1><<<NN / 8, 256, 0, stream>>>((const unsigned*)yh, zh, cnt, col);
  // 4. hop 2: out = dinv * (A+I) zh
  gather_kernel<1, 0><<<NN / 8, 256, 0, stream>>>((const unsigned*)zh, out, cnt, col);
}